// Round 1
// baseline (433.298 us; speedup 1.0000x reference)
//
#include <hip/hip_runtime.h>
#include <hip/hip_bf16.h>
#include <stdint.h>

typedef unsigned short u16;
typedef __bf16 bf16x8 __attribute__((ext_vector_type(8)));
typedef float f32x4 __attribute__((ext_vector_type(4)));

#define M_TOT 8192   // B*S
#define N_TOT 4096   // reduction dim (n)
#define K_TOT 4096   // output dim (k)
#define BM 128
#define BN 128
#define BK 64

// round-to-nearest-even fp32 -> bf16 (inputs are normal floats; NaN not expected)
__device__ __forceinline__ u16 f2bf(float f) {
    union { float f; uint32_t u; } v; v.f = f;
    uint32_t u = v.u;
    return (u16)((u + 0x7fffu + ((u >> 16) & 1u)) >> 16);
}

// ---- pre-pass 1: x fp32 -> bf16, 8 elems/thread -------------------------------
__global__ __launch_bounds__(256) void cvt_x_kernel(const float* __restrict__ x,
                                                    u16* __restrict__ xb) {
    const int i = blockIdx.x * blockDim.x + threadIdx.x;     // one per 8 elems
    const float4* p = (const float4*)x + (size_t)i * 2;
    float4 v0 = p[0], v1 = p[1];
    uint4 o;
    o.x = (uint32_t)f2bf(v0.x) | ((uint32_t)f2bf(v0.y) << 16);
    o.y = (uint32_t)f2bf(v0.z) | ((uint32_t)f2bf(v0.w) << 16);
    o.z = (uint32_t)f2bf(v1.x) | ((uint32_t)f2bf(v1.y) << 16);
    o.w = (uint32_t)f2bf(v1.z) | ((uint32_t)f2bf(v1.w) << 16);
    *((uint4*)(xb + (size_t)i * 8)) = o;
}

// ---- pre-pass 2: dequantize W_q -> bf16, 8 elems/thread -----------------------
// W_deq[k,n] = (Q[k,n] - zeros[k, n/64]) * scales[k, n/64] * mu2[k] * mu1[n]
__global__ __launch_bounds__(256) void deq_w_kernel(const int* __restrict__ wq,
                                                    const float* __restrict__ scales,
                                                    const float* __restrict__ zeros,
                                                    const float* __restrict__ mu1,
                                                    const float* __restrict__ mu2,
                                                    u16* __restrict__ wb) {
    const int i = blockIdx.x * blockDim.x + threadIdx.x;
    const int k  = i >> 9;              // 512 threads per row of 4096
    const int n0 = (i & 511) << 3;      // 8 contiguous n, same group (8 | 64)
    const int g  = n0 >> 6;
    const float z  = zeros[k * 64 + g];
    const float sm = scales[k * 64 + g] * mu2[k];
    const int4* qp = (const int4*)(wq + (size_t)k * N_TOT + n0);
    int4 q0 = qp[0], q1 = qp[1];
    const float4* mp = (const float4*)(mu1 + n0);
    float4 u0 = mp[0], u1 = mp[1];
    uint4 o;
    o.x = (uint32_t)f2bf(((float)q0.x - z) * sm * u0.x) |
          ((uint32_t)f2bf(((float)q0.y - z) * sm * u0.y) << 16);
    o.y = (uint32_t)f2bf(((float)q0.z - z) * sm * u0.z) |
          ((uint32_t)f2bf(((float)q0.w - z) * sm * u0.w) << 16);
    o.z = (uint32_t)f2bf(((float)q1.x - z) * sm * u1.x) |
          ((uint32_t)f2bf(((float)q1.y - z) * sm * u1.y) << 16);
    o.w = (uint32_t)f2bf(((float)q1.z - z) * sm * u1.z) |
          ((uint32_t)f2bf(((float)q1.w - z) * sm * u1.w) << 16);
    *((uint4*)(wb + (size_t)k * N_TOT + n0)) = o;
}

// ---- main GEMM: out[m,k] = sum_n xb[m,n]*wb[k,n] + bias[k] --------------------
// m97 structure: 128x128 tile, BK=64, 4 waves (2x2), global_load_lds width 16,
// linear LDS, 2 barriers per K-step.
__global__ __launch_bounds__(256) void gemm_kernel(const u16* __restrict__ Xb,
                                                   const u16* __restrict__ Wb,
                                                   const float* __restrict__ bias,
                                                   float* __restrict__ out) {
    __shared__ __align__(16) u16 As[BM * BK];   // 16 KB
    __shared__ __align__(16) u16 Bs[BN * BK];   // 16 KB

    // XCD-bijective swizzle (nwg = 2048, divisible by 8)
    const int nwg = gridDim.x;
    const int cpx = nwg >> 3;
    const int bid = blockIdx.x;
    const int swz = (bid & 7) * cpx + (bid >> 3);
    const int bm = swz >> 5;          // 64 M-tiles
    const int bn = swz & 31;          // 32 K-out tiles

    const int tid  = threadIdx.x;
    const int wave = tid >> 6;
    const int lane = tid & 63;
    const int wr = wave >> 1, wc = wave & 1;   // 2x2 waves, 64x64 out each

    // staging: each wave fills a contiguous 4KB quarter of each LDS tile.
    // issue i covers rows wave*32 + i*8 + (lane>>3), cols (lane&7)*8 .. +8
    const u16* aptr = Xb + (size_t)(bm * BM + wave * 32 + (lane >> 3)) * N_TOT + (lane & 7) * 8;
    const u16* bptr = Wb + (size_t)(bn * BN + wave * 32 + (lane >> 3)) * N_TOT + (lane & 7) * 8;
    u16* a_lds = As + wave * 2048;   // elements; wave-uniform base
    u16* b_lds = Bs + wave * 2048;

    f32x4 acc[4][4] = {};

    for (int n0 = 0; n0 < N_TOT; n0 += BK) {
        __syncthreads();   // previous tile fully consumed
        #pragma unroll
        for (int i = 0; i < 4; ++i) {
            __builtin_amdgcn_global_load_lds(
                (const __attribute__((address_space(1))) uint32_t*)(aptr + n0 + i * 8 * N_TOT),
                (__attribute__((address_space(3))) uint32_t*)(a_lds + i * 512), 16, 0, 0);
            __builtin_amdgcn_global_load_lds(
                (const __attribute__((address_space(1))) uint32_t*)(bptr + n0 + i * 8 * N_TOT),
                (__attribute__((address_space(3))) uint32_t*)(b_lds + i * 512), 16, 0, 0);
        }
        __syncthreads();   // compiler drains vmcnt before s_barrier -> tile ready

        #pragma unroll
        for (int kk = 0; kk < BK; kk += 32) {
            bf16x8 af[4], bfr[4];
            #pragma unroll
            for (int m = 0; m < 4; ++m)
                af[m] = *(const bf16x8*)(As + (wr * 64 + m * 16 + (lane & 15)) * BK
                                            + kk + (lane >> 4) * 8);
            #pragma unroll
            for (int n = 0; n < 4; ++n)
                bfr[n] = *(const bf16x8*)(Bs + (wc * 64 + n * 16 + (lane & 15)) * BK
                                             + kk + (lane >> 4) * 8);
            #pragma unroll
            for (int m = 0; m < 4; ++m)
                #pragma unroll
                for (int n = 0; n < 4; ++n)
                    acc[m][n] = __builtin_amdgcn_mfma_f32_16x16x32_bf16(
                        af[m], bfr[n], acc[m][n], 0, 0, 0);
        }
    }

    // epilogue: C/D layout col = lane&15 (k-out), row = (lane>>4)*4 + r (m)
    const int col_base = bn * BN + wc * 64 + (lane & 15);
    const int row_base = bm * BM + wr * 64 + ((lane >> 4) << 2);
    #pragma unroll
    for (int n = 0; n < 4; ++n) {
        const int col = col_base + n * 16;
        const float bv = bias[col];
        #pragma unroll
        for (int m = 0; m < 4; ++m) {
            const int row = row_base + m * 16;
            #pragma unroll
            for (int r = 0; r < 4; ++r)
                out[(size_t)(row + r) * K_TOT + col] = acc[m][n][r] + bv;
        }
    }
}

extern "C" void kernel_launch(void* const* d_in, const int* in_sizes, int n_in,
                              void* d_out, int out_size, void* d_ws, size_t ws_size,
                              hipStream_t stream) {
    const float* x      = (const float*)d_in[0];
    const float* scales = (const float*)d_in[1];
    const float* zeros  = (const float*)d_in[2];
    const float* mu1    = (const float*)d_in[3];
    const float* mu2    = (const float*)d_in[4];
    const float* bias   = (const float*)d_in[5];
    const int*   wq     = (const int*)d_in[6];
    float* out = (float*)d_out;

    // workspace: xb = 8192*4096 bf16 (64 MiB), wb = 4096*4096 bf16 (32 MiB)
    u16* xb = (u16*)d_ws;
    u16* wb = (u16*)d_ws + (size_t)M_TOT * N_TOT;

    cvt_x_kernel<<<(M_TOT * N_TOT / 8) / 256, 256, 0, stream>>>(x, xb);
    deq_w_kernel<<<(K_TOT * N_TOT / 8) / 256, 256, 0, stream>>>(wq, scales, zeros, mu1, mu2, wb);
    gemm_kernel<<<(M_TOT / BM) * (K_TOT / BN), 256, 0, stream>>>(xb, wb, bias, out);
}

// Round 2
// 368.888 us; speedup vs baseline: 1.1746x; 1.1746x over previous
//
#include <hip/hip_runtime.h>
#include <hip/hip_bf16.h>
#include <stdint.h>

typedef unsigned short u16;
typedef __bf16 bf16x8 __attribute__((ext_vector_type(8)));
typedef float f32x4 __attribute__((ext_vector_type(4)));

#define M_TOT 8192   // B*S
#define N_TOT 4096   // reduction dim (n)
#define K_TOT 4096   // output dim (k)
#define BM 128
#define BN 128
#define BK 64

// round-to-nearest-even fp32 -> bf16
__device__ __forceinline__ u16 f2bf(float f) {
    union { float f; uint32_t u; } v; v.f = f;
    uint32_t u = v.u;
    return (u16)((u + 0x7fffu + ((u >> 16) & 1u)) >> 16);
}

// ---- pre-pass 1: x fp32 -> bf16, 8 elems/thread -------------------------------
__global__ __launch_bounds__(256) void cvt_x_kernel(const float* __restrict__ x,
                                                    u16* __restrict__ xb) {
    const int i = blockIdx.x * blockDim.x + threadIdx.x;
    const float4* p = (const float4*)x + (size_t)i * 2;
    float4 v0 = p[0], v1 = p[1];
    uint4 o;
    o.x = (uint32_t)f2bf(v0.x) | ((uint32_t)f2bf(v0.y) << 16);
    o.y = (uint32_t)f2bf(v0.z) | ((uint32_t)f2bf(v0.w) << 16);
    o.z = (uint32_t)f2bf(v1.x) | ((uint32_t)f2bf(v1.y) << 16);
    o.w = (uint32_t)f2bf(v1.z) | ((uint32_t)f2bf(v1.w) << 16);
    *((uint4*)(xb + (size_t)i * 8)) = o;
}

// ---- pre-pass 2: dequantize W_q -> bf16, 8 elems/thread -----------------------
// W_deq[k,n] = (Q[k,n] - zeros[k, n/64]) * scales[k, n/64] * mu2[k] * mu1[n]
__global__ __launch_bounds__(256) void deq_w_kernel(const int* __restrict__ wq,
                                                    const float* __restrict__ scales,
                                                    const float* __restrict__ zeros,
                                                    const float* __restrict__ mu1,
                                                    const float* __restrict__ mu2,
                                                    u16* __restrict__ wb) {
    const int i = blockIdx.x * blockDim.x + threadIdx.x;
    const int k  = i >> 9;
    const int n0 = (i & 511) << 3;
    const int g  = n0 >> 6;
    const float z  = zeros[k * 64 + g];
    const float sm = scales[k * 64 + g] * mu2[k];
    const int4* qp = (const int4*)(wq + (size_t)k * N_TOT + n0);
    int4 q0 = qp[0], q1 = qp[1];
    const float4* mp = (const float4*)(mu1 + n0);
    float4 u0 = mp[0], u1 = mp[1];
    uint4 o;
    o.x = (uint32_t)f2bf(((float)q0.x - z) * sm * u0.x) |
          ((uint32_t)f2bf(((float)q0.y - z) * sm * u0.y) << 16);
    o.y = (uint32_t)f2bf(((float)q0.z - z) * sm * u0.z) |
          ((uint32_t)f2bf(((float)q0.w - z) * sm * u0.w) << 16);
    o.z = (uint32_t)f2bf(((float)q1.x - z) * sm * u1.x) |
          ((uint32_t)f2bf(((float)q1.y - z) * sm * u1.y) << 16);
    o.w = (uint32_t)f2bf(((float)q1.z - z) * sm * u1.w) |
          ((uint32_t)f2bf(((float)q1.w - z) * sm * u1.w) << 16);
    // NOTE: fixed below — do not use this line (kept for clarity of diff)
    o.w = (uint32_t)f2bf(((float)q1.z - z) * sm * u1.z) |
          ((uint32_t)f2bf(((float)q1.w - z) * sm * u1.w) << 16);
    *((uint4*)(wb + (size_t)k * N_TOT + n0)) = o;
}

// ---- main GEMM: out[m,k] = sum_n xb[m,n]*wb[k,n] + bias[k] --------------------
// m97 structure + T2 both-sides XOR swizzle:
//   logical (row, colByte) stored at physical row*128 + (colByte ^ ((row&7)<<4)).
//   gload_lds writes linearly, so the GLOBAL source column is inverse-permuted
//   (valid: staging lane l covers row with row&7 == l>>3), and the ds_read
//   address applies the same XOR (fragment row&7 == lane&7).
__global__ __launch_bounds__(256) void gemm_kernel(const u16* __restrict__ Xb,
                                                   const u16* __restrict__ Wb,
                                                   const float* __restrict__ bias,
                                                   float* __restrict__ out) {
    __shared__ __align__(16) u16 As[BM * BK];   // 16 KB
    __shared__ __align__(16) u16 Bs[BN * BK];   // 16 KB

    // XCD-bijective swizzle (nwg = 2048, divisible by 8)
    const int nwg = gridDim.x;
    const int cpx = nwg >> 3;
    const int bid = blockIdx.x;
    const int swz = (bid & 7) * cpx + (bid >> 3);
    const int bm = swz >> 5;          // 64 M-tiles
    const int bn = swz & 31;          // 32 K-out tiles

    const int tid  = threadIdx.x;
    const int wave = tid >> 6;
    const int lane = tid & 63;
    const int wr = wave >> 1, wc = wave & 1;   // 2x2 waves, 64x64 out each

    // staging: lane l of issue i covers logical row (wave*32 + i*8 + (l>>3)).
    // pre-swizzled global column so physical LDS slot (l&7) holds logical
    // column ((l&7) ^ (l>>3)).
    const int stage_col = (((lane & 7) ^ (lane >> 3)) << 3);  // elements
    const u16* aptr = Xb + (size_t)(bm * BM + wave * 32 + (lane >> 3)) * N_TOT + stage_col;
    const u16* bptr = Wb + (size_t)(bn * BN + wave * 32 + (lane >> 3)) * N_TOT + stage_col;
    u16* a_lds = As + wave * 2048;   // wave-uniform base, linear dest
    u16* b_lds = Bs + wave * 2048;

    // read-side swizzle term (elements): fragment row&7 == lane&7
    const int rd_swz = (lane & 7) << 3;

    f32x4 acc[4][4] = {};

    for (int n0 = 0; n0 < N_TOT; n0 += BK) {
        __syncthreads();
        #pragma unroll
        for (int i = 0; i < 4; ++i) {
            __builtin_amdgcn_global_load_lds(
                (const __attribute__((address_space(1))) uint32_t*)(aptr + n0 + i * 8 * N_TOT),
                (__attribute__((address_space(3))) uint32_t*)(a_lds + i * 512), 16, 0, 0);
            __builtin_amdgcn_global_load_lds(
                (const __attribute__((address_space(1))) uint32_t*)(bptr + n0 + i * 8 * N_TOT),
                (__attribute__((address_space(3))) uint32_t*)(b_lds + i * 512), 16, 0, 0);
        }
        __syncthreads();

        #pragma unroll
        for (int kk = 0; kk < BK; kk += 32) {
            bf16x8 af[4], bfr[4];
            const int ccol = (kk + ((lane >> 4) << 3)) ^ rd_swz;  // swizzled col
            #pragma unroll
            for (int m = 0; m < 4; ++m)
                af[m] = *(const bf16x8*)(As + (wr * 64 + m * 16 + (lane & 15)) * BK + ccol);
            #pragma unroll
            for (int n = 0; n < 4; ++n)
                bfr[n] = *(const bf16x8*)(Bs + (wc * 64 + n * 16 + (lane & 15)) * BK + ccol);
            #pragma unroll
            for (int m = 0; m < 4; ++m)
                #pragma unroll
                for (int n = 0; n < 4; ++n)
                    acc[m][n] = __builtin_amdgcn_mfma_f32_16x16x32_bf16(
                        af[m], bfr[n], acc[m][n], 0, 0, 0);
        }
    }

    // epilogue: C/D layout col = lane&15 (k-out), row = (lane>>4)*4 + r (m)
    const int col_base = bn * BN + wc * 64 + (lane & 15);
    const int row_base = bm * BM + wr * 64 + ((lane >> 4) << 2);
    #pragma unroll
    for (int n = 0; n < 4; ++n) {
        const int col = col_base + n * 16;
        const float bv = bias[col];
        #pragma unroll
        for (int m = 0; m < 4; ++m) {
            const int row = row_base + m * 16;
            #pragma unroll
            for (int r = 0; r < 4; ++r)
                out[(size_t)(row + r) * K_TOT + col] = acc[m][n][r] + bv;
        }
    }
}

extern "C" void kernel_launch(void* const* d_in, const int* in_sizes, int n_in,
                              void* d_out, int out_size, void* d_ws, size_t ws_size,
                              hipStream_t stream) {
    const float* x      = (const float*)d_in[0];
    const float* scales = (const float*)d_in[1];
    const float* zeros  = (const float*)d_in[2];
    const float* mu1    = (const float*)d_in[3];
    const float* mu2    = (const float*)d_in[4];
    const float* bias   = (const float*)d_in[5];
    const int*   wq     = (const int*)d_in[6];
    float* out = (float*)d_out;

    u16* xb = (u16*)d_ws;                                 // 64 MiB
    u16* wb = (u16*)d_ws + (size_t)M_TOT * N_TOT;         // 32 MiB

    cvt_x_kernel<<<(M_TOT * N_TOT / 8) / 256, 256, 0, stream>>>(x, xb);
    deq_w_kernel<<<(K_TOT * N_TOT / 8) / 256, 256, 0, stream>>>(wq, scales, zeros, mu1, mu2, wb);
    gemm_kernel<<<(M_TOT / BM) * (K_TOT / BN), 256, 0, stream>>>(xb, wb, bias, out);
}

// Round 3
// 287.056 us; speedup vs baseline: 1.5095x; 1.2851x over previous
//
#include <hip/hip_runtime.h>
#include <hip/hip_bf16.h>
#include <stdint.h>
#include <type_traits>

typedef unsigned short u16;
typedef __bf16 bf16x8 __attribute__((ext_vector_type(8)));
typedef float f32x4 __attribute__((ext_vector_type(4)));

#define M_TOT 8192   // B*S
#define N_TOT 4096   // reduction dim
#define K_TOT 4096   // output dim
#define BM 256
#define BN 256
#define BK 64
#define NT 64        // N_TOT / BK

// LDS geometry in u16 elements: [slot][A:2 halves | B:2 halves][128][64]
#define HALF_EL 8192     // 128 rows * 64 cols
#define B_OFF   16384
#define SLOT_EL 32768    // 64 KiB per slot

template <int V> using ic = std::integral_constant<int, V>;
template <bool V> using bc = std::integral_constant<bool, V>;

__device__ __forceinline__ u16 f2bf(float f) {
    union { float f; uint32_t u; } v; v.f = f;
    uint32_t u = v.u;
    return (u16)((u + 0x7fffu + ((u >> 16) & 1u)) >> 16);
}

// ---- pre-pass 1: x fp32 -> bf16 ----------------------------------------------
__global__ __launch_bounds__(256) void cvt_x_kernel(const float* __restrict__ x,
                                                    u16* __restrict__ xb) {
    const int i = blockIdx.x * blockDim.x + threadIdx.x;
    const float4* p = (const float4*)x + (size_t)i * 2;
    float4 v0 = p[0], v1 = p[1];
    uint4 o;
    o.x = (uint32_t)f2bf(v0.x) | ((uint32_t)f2bf(v0.y) << 16);
    o.y = (uint32_t)f2bf(v0.z) | ((uint32_t)f2bf(v0.w) << 16);
    o.z = (uint32_t)f2bf(v1.x) | ((uint32_t)f2bf(v1.y) << 16);
    o.w = (uint32_t)f2bf(v1.z) | ((uint32_t)f2bf(v1.w) << 16);
    *((uint4*)(xb + (size_t)i * 8)) = o;
}

// ---- pre-pass 2: dequantize W_q -> bf16 --------------------------------------
__global__ __launch_bounds__(256) void deq_w_kernel(const int* __restrict__ wq,
                                                    const float* __restrict__ scales,
                                                    const float* __restrict__ zeros,
                                                    const float* __restrict__ mu1,
                                                    const float* __restrict__ mu2,
                                                    u16* __restrict__ wb) {
    const int i = blockIdx.x * blockDim.x + threadIdx.x;
    const int k  = i >> 9;
    const int n0 = (i & 511) << 3;
    const int g  = n0 >> 6;
    const float z  = zeros[k * 64 + g];
    const float sm = scales[k * 64 + g] * mu2[k];
    const int4* qp = (const int4*)(wq + (size_t)k * N_TOT + n0);
    int4 q0 = qp[0], q1 = qp[1];
    const float4* mp = (const float4*)(mu1 + n0);
    float4 u0 = mp[0], u1 = mp[1];
    uint4 o;
    o.x = (uint32_t)f2bf(((float)q0.x - z) * sm * u0.x) |
          ((uint32_t)f2bf(((float)q0.y - z) * sm * u0.y) << 16);
    o.y = (uint32_t)f2bf(((float)q0.z - z) * sm * u0.z) |
          ((uint32_t)f2bf(((float)q0.w - z) * sm * u0.w) << 16);
    o.z = (uint32_t)f2bf(((float)q1.x - z) * sm * u1.x) |
          ((uint32_t)f2bf(((float)q1.y - z) * sm * u1.y) << 16);
    o.w = (uint32_t)f2bf(((float)q1.z - z) * sm * u1.z) |
          ((uint32_t)f2bf(((float)q1.w - z) * sm * u1.w) << 16);
    *((uint4*)(wb + (size_t)k * N_TOT + n0)) = o;
}

// ---- main GEMM: 256x256 8-phase template (T2+T3+T4+T5) -----------------------
// 8 waves (2M x 4N), per-wave out 128x64. K-tile BK=64, double-buffered LDS.
// Per K-tile: 4 phases, phase p computes quadrant (mh=p>>1, nh=p&1) with K=64
// (16 MFMA). Half-tile deaths: A0@p1, B0@p2, A1@p3, B1@p3. Staging:
// p0->(t+1).A1, p1->(t+1).B1, p2->(t+2).A0, p3->(t+2).B0 (strictly post-death).
// Boundary s_waitcnt vmcnt(4) keeps the two newest half-tiles in flight.
// LDS XOR swizzle (proven R2): physical colByte = logical ^ ((row&7)<<4);
// linear gload_lds dest + inverse-swizzled global source + swizzled ds_read.
__global__ __launch_bounds__(512, 2) void gemm_kernel(const u16* __restrict__ Xb,
                                                      const u16* __restrict__ Wb,
                                                      const float* __restrict__ bias,
                                                      float* __restrict__ out) {
    __shared__ __align__(16) u16 lds[2 * SLOT_EL];   // 128 KiB

    // XCD-bijective swizzle: nwg = 512, divisible by 8
    const int bid = blockIdx.x;
    const int cpx = gridDim.x >> 3;
    const int swz = (bid & 7) * cpx + (bid >> 3);
    const int bm = swz >> 4;    // 32 M-tiles
    const int bn = swz & 15;    // 16 out-tiles

    const int tid  = threadIdx.x;
    const int w    = tid >> 6;
    const int lane = tid & 63;
    const int wm = w >> 2, wn = w & 3;

    // --- staging addressing (per half-tile: 2 x global_load_lds per thread) ---
    // lane l of issue i: LDS row (w*16 + i*8 + (l>>3)), physical col (l&7)*16B;
    // global source column pre-swizzled so logical col = ((l&7)^(l>>3))*8.
    const int scol = (((lane & 7) ^ (lane >> 3)) << 3);
    const u16* aS = Xb + (size_t)(bm * BM + w * 16 + (lane >> 3)) * N_TOT + scol;
    const u16* bS = Wb + (size_t)(bn * BN + w * 16 + (lane >> 3)) * N_TOT + scol;

    auto stageA = [&](int slot, int h, int u) {
        const u16* s = aS + (size_t)(h * 128) * N_TOT + u * BK;
        u16* d = &lds[slot * SLOT_EL + h * HALF_EL + w * 1024];   // wave-uniform
        __builtin_amdgcn_global_load_lds(
            (const __attribute__((address_space(1))) uint32_t*)s,
            (__attribute__((address_space(3))) uint32_t*)d, 16, 0, 0);
        __builtin_amdgcn_global_load_lds(
            (const __attribute__((address_space(1))) uint32_t*)(s + (size_t)8 * N_TOT),
            (__attribute__((address_space(3))) uint32_t*)(d + 512), 16, 0, 0);
    };
    auto stageB = [&](int slot, int h, int u) {
        const u16* s = bS + (size_t)(h * 128) * N_TOT + u * BK;
        u16* d = &lds[slot * SLOT_EL + B_OFF + h * HALF_EL + w * 1024];
        __builtin_amdgcn_global_load_lds(
            (const __attribute__((address_space(1))) uint32_t*)s,
            (__attribute__((address_space(3))) uint32_t*)d, 16, 0, 0);
        __builtin_amdgcn_global_load_lds(
            (const __attribute__((address_space(1))) uint32_t*)(s + (size_t)8 * N_TOT),
            (__attribute__((address_space(3))) uint32_t*)(d + 512), 16, 0, 0);
    };

    // --- fragment read addressing (u16 elements) ---
    // row term: (frag row base + lane&15)*64 ; col: (ks*32 + (lane>>4)*8) ^ ((lane&7)*8)
    const int cc0 = (((lane >> 4) << 3)) ^ ((lane & 7) << 3);
    const int rA  = ((wm << 4) + (lane & 15)) << 6;
    const int rB  = ((wn << 4) + (lane & 15)) << 6;

    f32x4 acc[2][2][4][2] = {};
    bf16x8 af[4][2], bf[2][2];

    auto phase = [&](auto Pc, auto Sc, int t) {
        constexpr int P = Pc.value;
        constexpr bool S = Sc.value;
        constexpr int mh = P >> 1, nh = P & 1;
        const int slot = (t & 1) * SLOT_EL;
        // ds-reads: A only on mh-change phases (p0, p2); B every phase
        if constexpr ((P & 1) == 0) {
            #pragma unroll
            for (int j = 0; j < 4; ++j) {
                af[j][0] = *(const bf16x8*)&lds[slot + mh * HALF_EL + rA + j * 2048 + cc0];
                af[j][1] = *(const bf16x8*)&lds[slot + mh * HALF_EL + rA + j * 2048 + (cc0 ^ 32)];
            }
        }
        #pragma unroll
        for (int j2 = 0; j2 < 2; ++j2) {
            bf[j2][0] = *(const bf16x8*)&lds[slot + B_OFF + nh * HALF_EL + rB + j2 * 4096 + cc0];
            bf[j2][1] = *(const bf16x8*)&lds[slot + B_OFF + nh * HALF_EL + rB + j2 * 4096 + (cc0 ^ 32)];
        }
        // stage one half-tile (post-death targets, see header comment)
        if constexpr (S) {
            if constexpr (P == 0) stageA((t + 1) & 1, 1, t + 1);
            if constexpr (P == 1) stageB((t + 1) & 1, 1, t + 1);
            if constexpr (P == 2) stageA(t & 1, 0, t + 2);
            if constexpr (P == 3) stageB(t & 1, 0, t + 2);
        }
        __builtin_amdgcn_s_barrier();
        asm volatile("s_waitcnt lgkmcnt(0)" ::: "memory");
        __builtin_amdgcn_sched_barrier(0);
        __builtin_amdgcn_s_setprio(1);
        #pragma unroll
        for (int j = 0; j < 4; ++j)
            #pragma unroll
            for (int j2 = 0; j2 < 2; ++j2)
                #pragma unroll
                for (int ks = 0; ks < 2; ++ks)
                    acc[mh][nh][j][j2] = __builtin_amdgcn_mfma_f32_16x16x32_bf16(
                        af[j][ks], bf[j2][ks], acc[mh][nh][j][j2], 0, 0, 0);
        __builtin_amdgcn_s_setprio(0);
    };

    auto ktile = [&](auto Mc, auto Vc, int t) {
        constexpr int MASK = Mc.value;
        constexpr int V = Vc.value;
        phase(ic<0>{}, bc<(MASK & 1) != 0>{}, t);
        __builtin_amdgcn_s_barrier();
        phase(ic<1>{}, bc<(MASK & 2) != 0>{}, t);
        __builtin_amdgcn_s_barrier();
        phase(ic<2>{}, bc<(MASK & 4) != 0>{}, t);
        __builtin_amdgcn_s_barrier();
        phase(ic<3>{}, bc<(MASK & 8) != 0>{}, t);
        if constexpr (V == 4) asm volatile("s_waitcnt vmcnt(4)" ::: "memory");
        else if constexpr (V == 0) asm volatile("s_waitcnt vmcnt(0)" ::: "memory");
        __builtin_amdgcn_s_barrier();
    };

    // prologue: tile0 complete (A0,B0,A1,B1) + tile1 (A0,B0); leave tile1 in flight
    stageA(0, 0, 0); stageB(0, 0, 0); stageA(0, 1, 0); stageB(0, 1, 0);
    stageA(1, 0, 1); stageB(1, 0, 1);
    asm volatile("s_waitcnt vmcnt(4)" ::: "memory");
    __builtin_amdgcn_s_barrier();

    for (int t = 0; t < NT - 2; ++t) ktile(ic<0xF>{}, ic<4>{}, t);
    ktile(ic<0x3>{}, ic<0>{}, NT - 2);   // stages (NT-1).A1/B1 only; full drain
    ktile(ic<0x0>{}, ic<-1>{}, NT - 1);  // last tile, no staging

    // epilogue: C/D layout col = lane&15 (out-dim), row = (lane>>4)*4 + rr (M)
    #pragma unroll
    for (int mh_ = 0; mh_ < 2; ++mh_)
        #pragma unroll
        for (int j = 0; j < 4; ++j)
            #pragma unroll
            for (int rr = 0; rr < 4; ++rr) {
                const int row = bm * BM + mh_ * 128 + j * 32 + wm * 16 + ((lane >> 4) << 2) + rr;
                float* orow = out + (size_t)row * K_TOT;
                #pragma unroll
                for (int nh_ = 0; nh_ < 2; ++nh_)
                    #pragma unroll
                    for (int j2 = 0; j2 < 2; ++j2) {
                        const int col = bn * BN + nh_ * 128 + j2 * 64 + wn * 16 + (lane & 15);
                        orow[col] = acc[mh_][nh_][j][j2][rr] + bias[col];
                    }
            }
}

extern "C" void kernel_launch(void* const* d_in, const int* in_sizes, int n_in,
                              void* d_out, int out_size, void* d_ws, size_t ws_size,
                              hipStream_t stream) {
    const float* x      = (const float*)d_in[0];
    const float* scales = (const float*)d_in[1];
    const float* zeros  = (const float*)d_in[2];
    const float* mu1    = (const float*)d_in[3];
    const float* mu2    = (const float*)d_in[4];
    const float* bias   = (const float*)d_in[5];
    const int*   wq     = (const int*)d_in[6];
    float* out = (float*)d_out;

    u16* xb = (u16*)d_ws;                                 // 64 MiB
    u16* wb = (u16*)d_ws + (size_t)M_TOT * N_TOT;         // 32 MiB

    cvt_x_kernel<<<(M_TOT * N_TOT / 8) / 256, 256, 0, stream>>>(x, xb);
    deq_w_kernel<<<(K_TOT * N_TOT / 8) / 256, 256, 0, stream>>>(wq, scales, zeros, mu1, mu2, wb);
    gemm_kernel<<<(M_TOT / BM) * (K_TOT / BN), 512, 0, stream>>>(xb, wb, bias, out);
}

// Round 4
// 280.370 us; speedup vs baseline: 1.5455x; 1.0238x over previous
//
#include <hip/hip_runtime.h>
#include <hip/hip_bf16.h>
#include <stdint.h>
#include <type_traits>

typedef unsigned short u16;
typedef __bf16 bf16x8 __attribute__((ext_vector_type(8)));
typedef float f32x4 __attribute__((ext_vector_type(4)));

#define M_TOT 8192   // B*S
#define N_TOT 4096   // reduction dim
#define K_TOT 4096   // output dim
#define BM 256
#define BN 256
#define BK 64
#define NT 64        // N_TOT / BK

// LDS geometry in u16 elements: [slot][A:2 halves | B:2 halves][128][64]
#define HALF_EL 8192     // 128 rows * 64 cols
#define B_OFF   16384
#define SLOT_EL 32768    // 64 KiB per slot

template <int V> using ic = std::integral_constant<int, V>;
template <bool V> using bc = std::integral_constant<bool, V>;

__device__ __forceinline__ u16 f2bf(float f) {
    union { float f; uint32_t u; } v; v.f = f;
    uint32_t u = v.u;
    return (u16)((u + 0x7fffu + ((u >> 16) & 1u)) >> 16);
}

// ---- pre-pass 1: x fp32 -> bf16 ----------------------------------------------
__global__ __launch_bounds__(256) void cvt_x_kernel(const float* __restrict__ x,
                                                    u16* __restrict__ xb) {
    const int i = blockIdx.x * blockDim.x + threadIdx.x;
    const float4* p = (const float4*)x + (size_t)i * 2;
    float4 v0 = p[0], v1 = p[1];
    uint4 o;
    o.x = (uint32_t)f2bf(v0.x) | ((uint32_t)f2bf(v0.y) << 16);
    o.y = (uint32_t)f2bf(v0.z) | ((uint32_t)f2bf(v0.w) << 16);
    o.z = (uint32_t)f2bf(v1.x) | ((uint32_t)f2bf(v1.y) << 16);
    o.w = (uint32_t)f2bf(v1.z) | ((uint32_t)f2bf(v1.w) << 16);
    *((uint4*)(xb + (size_t)i * 8)) = o;
}

// ---- pre-pass 2: dequantize W_q -> bf16 --------------------------------------
__global__ __launch_bounds__(256) void deq_w_kernel(const int* __restrict__ wq,
                                                    const float* __restrict__ scales,
                                                    const float* __restrict__ zeros,
                                                    const float* __restrict__ mu1,
                                                    const float* __restrict__ mu2,
                                                    u16* __restrict__ wb) {
    const int i = blockIdx.x * blockDim.x + threadIdx.x;
    const int k  = i >> 9;
    const int n0 = (i & 511) << 3;
    const int g  = n0 >> 6;
    const float z  = zeros[k * 64 + g];
    const float sm = scales[k * 64 + g] * mu2[k];
    const int4* qp = (const int4*)(wq + (size_t)k * N_TOT + n0);
    int4 q0 = qp[0], q1 = qp[1];
    const float4* mp = (const float4*)(mu1 + n0);
    float4 u0 = mp[0], u1 = mp[1];
    uint4 o;
    o.x = (uint32_t)f2bf(((float)q0.x - z) * sm * u0.x) |
          ((uint32_t)f2bf(((float)q0.y - z) * sm * u0.y) << 16);
    o.y = (uint32_t)f2bf(((float)q0.z - z) * sm * u0.z) |
          ((uint32_t)f2bf(((float)q0.w - z) * sm * u0.w) << 16);
    o.z = (uint32_t)f2bf(((float)q1.x - z) * sm * u1.x) |
          ((uint32_t)f2bf(((float)q1.y - z) * sm * u1.y) << 16);
    o.w = (uint32_t)f2bf(((float)q1.z - z) * sm * u1.z) |
          ((uint32_t)f2bf(((float)q1.w - z) * sm * u1.w) << 16);
    *((uint4*)(wb + (size_t)k * N_TOT + n0)) = o;
}

// ---- main GEMM: 256x256 8-phase, full fragment register-caching --------------
// 8 waves (2M x 4N), per-wave out 128x64, BK=64, double-buffered LDS.
// Phase p computes quadrant (mh=p>>1, nh=p&1), 16 MFMA.
// ds-reads: p0 reads A0+B0 frags, p1 reads A1+B1; p2/p3 run from registers.
// => all 4 buffers of tile t dead by end of p1; other slot dead before t starts.
// Staging (all to other slot): p0->(t+1).A0, p1->(t+1).B0, p2->(t+1).A1,
// p3->(t+1).B1. Counted waits: boundary vmcnt(4) (leaves A1,B1 in flight),
// p0-end vmcnt(2) (leaves p0's new stage). Last tile: p0-end vmcnt(0).
// LDS XOR swizzle (proven R2/R3): physical col = logical ^ ((row&7)*8 el);
// linear gload_lds dest + inverse-swizzled global source + swizzled ds_read.
__global__ __launch_bounds__(512, 2) void gemm_kernel(const u16* __restrict__ Xb,
                                                      const u16* __restrict__ Wb,
                                                      const float* __restrict__ bias,
                                                      float* __restrict__ out) {
    __shared__ __align__(16) u16 lds[2 * SLOT_EL];   // 128 KiB

    // XCD-bijective swizzle: nwg = 512, divisible by 8
    const int bid = blockIdx.x;
    const int cpx = gridDim.x >> 3;
    const int swz = (bid & 7) * cpx + (bid >> 3);
    const int bm = swz >> 4;    // 32 M-tiles
    const int bn = swz & 15;    // 16 out-tiles

    const int tid  = threadIdx.x;
    const int w    = tid >> 6;
    const int lane = tid & 63;
    const int wm = w >> 2, wn = w & 3;

    // --- staging addressing: lane l, issue i covers LDS row (w*16 + i*8 + (l>>3)),
    // physical col (l&7)*16B; global col pre-swizzled: ((l&7)^(l>>3))*8 elems.
    const int scol = (((lane & 7) ^ (lane >> 3)) << 3);
    const u16* aS = Xb + (size_t)(bm * BM + w * 16 + (lane >> 3)) * N_TOT + scol;
    const u16* bS = Wb + (size_t)(bn * BN + w * 16 + (lane >> 3)) * N_TOT + scol;

    auto stageA = [&](int slot, int h, int u) {
        const u16* s = aS + (size_t)(h * 128) * N_TOT + u * BK;
        u16* d = &lds[slot * SLOT_EL + h * HALF_EL + w * 1024];   // wave-uniform
        __builtin_amdgcn_global_load_lds(
            (const __attribute__((address_space(1))) uint32_t*)s,
            (__attribute__((address_space(3))) uint32_t*)d, 16, 0, 0);
        __builtin_amdgcn_global_load_lds(
            (const __attribute__((address_space(1))) uint32_t*)(s + (size_t)8 * N_TOT),
            (__attribute__((address_space(3))) uint32_t*)(d + 512), 16, 0, 0);
    };
    auto stageB = [&](int slot, int h, int u) {
        const u16* s = bS + (size_t)(h * 128) * N_TOT + u * BK;
        u16* d = &lds[slot * SLOT_EL + B_OFF + h * HALF_EL + w * 1024];
        __builtin_amdgcn_global_load_lds(
            (const __attribute__((address_space(1))) uint32_t*)s,
            (__attribute__((address_space(3))) uint32_t*)d, 16, 0, 0);
        __builtin_amdgcn_global_load_lds(
            (const __attribute__((address_space(1))) uint32_t*)(s + (size_t)8 * N_TOT),
            (__attribute__((address_space(3))) uint32_t*)(d + 512), 16, 0, 0);
    };

    // --- fragment read addressing (u16 elements) ---
    const int cc0 = (((lane >> 4) << 3)) ^ ((lane & 7) << 3);
    const int rA  = ((wm << 4) + (lane & 15)) << 6;
    const int rB  = ((wn << 4) + (lane & 15)) << 6;

    f32x4 acc[2][2][4][2] = {};
    bf16x8 af[2][4][2];   // [mh][j][ks]
    bf16x8 bf[2][2][2];   // [nh][j2][ks]

    auto phase = [&](auto Pc, auto Sc, auto Wc, int t) {
        constexpr int P = Pc.value;
        constexpr bool S = Sc.value;
        constexpr int W = Wc.value;      // vmcnt before closing barrier; -1 = none
        constexpr int mh = P >> 1, nh = P & 1;
        const int slot = (t & 1) * SLOT_EL;
        if constexpr (P == 0 || P == 1) {
            // P==0: read A-half0 + B-half0; P==1: read A-half1 + B-half1
            #pragma unroll
            for (int j = 0; j < 4; ++j) {
                af[P][j][0] = *(const bf16x8*)&lds[slot + P * HALF_EL + rA + j * 2048 + cc0];
                af[P][j][1] = *(const bf16x8*)&lds[slot + P * HALF_EL + rA + j * 2048 + (cc0 ^ 32)];
            }
            #pragma unroll
            for (int j2 = 0; j2 < 2; ++j2) {
                bf[P][j2][0] = *(const bf16x8*)&lds[slot + B_OFF + P * HALF_EL + rB + j2 * 4096 + cc0];
                bf[P][j2][1] = *(const bf16x8*)&lds[slot + B_OFF + P * HALF_EL + rB + j2 * 4096 + (cc0 ^ 32)];
            }
        }
        if constexpr (S) {
            if constexpr (P == 0) stageA((t + 1) & 1, 0, t + 1);
            if constexpr (P == 1) stageB((t + 1) & 1, 0, t + 1);
            if constexpr (P == 2) stageA((t + 1) & 1, 1, t + 1);
            if constexpr (P == 3) stageB((t + 1) & 1, 1, t + 1);
        }
        __builtin_amdgcn_s_barrier();
        asm volatile("s_waitcnt lgkmcnt(0)" ::: "memory");
        __builtin_amdgcn_sched_barrier(0);
        __builtin_amdgcn_s_setprio(1);
        #pragma unroll
        for (int j = 0; j < 4; ++j)
            #pragma unroll
            for (int j2 = 0; j2 < 2; ++j2)
                #pragma unroll
                for (int ks = 0; ks < 2; ++ks)
                    acc[mh][nh][j][j2] = __builtin_amdgcn_mfma_f32_16x16x32_bf16(
                        af[mh][j][ks], bf[nh][j2][ks], acc[mh][nh][j][j2], 0, 0, 0);
        __builtin_amdgcn_s_setprio(0);
        if constexpr (W == 0)      asm volatile("s_waitcnt vmcnt(0)" ::: "memory");
        else if constexpr (W == 2) asm volatile("s_waitcnt vmcnt(2)" ::: "memory");
        else if constexpr (W == 4) asm volatile("s_waitcnt vmcnt(4)" ::: "memory");
        __builtin_amdgcn_s_barrier();
    };

    // prologue: stage tile0's 4 half-tiles; drain A0,B0 (leave A1,B1 in flight)
    stageA(0, 0, 0); stageB(0, 0, 0); stageA(0, 1, 0); stageB(0, 1, 0);
    asm volatile("s_waitcnt vmcnt(4)" ::: "memory");
    __builtin_amdgcn_s_barrier();

    for (int t = 0; t < NT - 1; ++t) {
        phase(ic<0>{}, bc<true>{}, ic<2>{}, t);    // reads A0,B0; stages (t+1).A0
        phase(ic<1>{}, bc<true>{}, ic<-1>{}, t);   // reads A1,B1; stages (t+1).B0
        phase(ic<2>{}, bc<true>{}, ic<-1>{}, t);   // reg-only;     stages (t+1).A1
        phase(ic<3>{}, bc<true>{}, ic<4>{}, t);    // reg-only;     stages (t+1).B1
    }
    // last tile: no staging; p0-end drains the in-flight A1,B1
    phase(ic<0>{}, bc<false>{}, ic<0>{}, NT - 1);
    phase(ic<1>{}, bc<false>{}, ic<-1>{}, NT - 1);
    phase(ic<2>{}, bc<false>{}, ic<-1>{}, NT - 1);
    phase(ic<3>{}, bc<false>{}, ic<-1>{}, NT - 1);

    // epilogue: C/D layout col = lane&15 (out-dim), row = (lane>>4)*4 + rr (M)
    #pragma unroll
    for (int mh_ = 0; mh_ < 2; ++mh_)
        #pragma unroll
        for (int j = 0; j < 4; ++j)
            #pragma unroll
            for (int rr = 0; rr < 4; ++rr) {
                const int row = bm * BM + mh_ * 128 + j * 32 + wm * 16 + ((lane >> 4) << 2) + rr;
                float* orow = out + (size_t)row * K_TOT;
                #pragma unroll
                for (int nh_ = 0; nh_ < 2; ++nh_)
                    #pragma unroll
                    for (int j2 = 0; j2 < 2; ++j2) {
                        const int col = bn * BN + nh_ * 128 + j2 * 64 + wn * 16 + (lane & 15);
                        orow[col] = acc[mh_][nh_][j][j2][rr] + bias[col];
                    }
            }
}

extern "C" void kernel_launch(void* const* d_in, const int* in_sizes, int n_in,
                              void* d_out, int out_size, void* d_ws, size_t ws_size,
                              hipStream_t stream) {
    const float* x      = (const float*)d_in[0];
    const float* scales = (const float*)d_in[1];
    const float* zeros  = (const float*)d_in[2];
    const float* mu1    = (const float*)d_in[3];
    const float* mu2    = (const float*)d_in[4];
    const float* bias   = (const float*)d_in[5];
    const int*   wq     = (const int*)d_in[6];
    float* out = (float*)d_out;

    u16* xb = (u16*)d_ws;                                 // 64 MiB
    u16* wb = (u16*)d_ws + (size_t)M_TOT * N_TOT;         // 32 MiB

    cvt_x_kernel<<<(M_TOT * N_TOT / 8) / 256, 256, 0, stream>>>(x, xb);
    deq_w_kernel<<<(K_TOT * N_TOT / 8) / 256, 256, 0, stream>>>(wq, scales, zeros, mu1, mu2, wb);
    gemm_kernel<<<(M_TOT / BM) * (K_TOT / BN), 512, 0, stream>>>(xb, wb, bias, out);
}

// Round 5
// 270.827 us; speedup vs baseline: 1.5999x; 1.0352x over previous
//
#include <hip/hip_runtime.h>
#include <hip/hip_bf16.h>
#include <stdint.h>

typedef unsigned short u16;
typedef __bf16 bf16x8 __attribute__((ext_vector_type(8)));
typedef float f32x4 __attribute__((ext_vector_type(4)));

#define M_TOT 8192   // B*S
#define N_TOT 4096   // reduction dim
#define K_TOT 4096   // output dim
#define BM 256
#define BN 256
#define BK 64
#define NT 64        // N_TOT / BK

// LDS geometry in u16 elements: [slot][A:2 halves | B:2 halves][128][64]
#define HALF_EL 8192     // 128 rows * 64 cols
#define B_OFF   16384
#define SLOT_EL 32768    // 64 KiB per slot

__device__ __forceinline__ u16 f2bf(float f) {
    union { float f; uint32_t u; } v; v.f = f;
    uint32_t u = v.u;
    return (u16)((u + 0x7fffu + ((u >> 16) & 1u)) >> 16);
}

// ---- pre-pass 1: x fp32 -> bf16 ----------------------------------------------
__global__ __launch_bounds__(256) void cvt_x_kernel(const float* __restrict__ x,
                                                    u16* __restrict__ xb) {
    const int i = blockIdx.x * blockDim.x + threadIdx.x;
    const float4* p = (const float4*)x + (size_t)i * 2;
    float4 v0 = p[0], v1 = p[1];
    uint4 o;
    o.x = (uint32_t)f2bf(v0.x) | ((uint32_t)f2bf(v0.y) << 16);
    o.y = (uint32_t)f2bf(v0.z) | ((uint32_t)f2bf(v0.w) << 16);
    o.z = (uint32_t)f2bf(v1.x) | ((uint32_t)f2bf(v1.y) << 16);
    o.w = (uint32_t)f2bf(v1.z) | ((uint32_t)f2bf(v1.w) << 16);
    *((uint4*)(xb + (size_t)i * 8)) = o;
}

// ---- pre-pass 2: dequantize W_q -> bf16 --------------------------------------
__global__ __launch_bounds__(256) void deq_w_kernel(const int* __restrict__ wq,
                                                    const float* __restrict__ scales,
                                                    const float* __restrict__ zeros,
                                                    const float* __restrict__ mu1,
                                                    const float* __restrict__ mu2,
                                                    u16* __restrict__ wb) {
    const int i = blockIdx.x * blockDim.x + threadIdx.x;
    const int k  = i >> 9;
    const int n0 = (i & 511) << 3;
    const int g  = n0 >> 6;
    const float z  = zeros[k * 64 + g];
    const float sm = scales[k * 64 + g] * mu2[k];
    const int4* qp = (const int4*)(wq + (size_t)k * N_TOT + n0);
    int4 q0 = qp[0], q1 = qp[1];
    const float4* mp = (const float4*)(mu1 + n0);
    float4 u0 = mp[0], u1 = mp[1];
    uint4 o;
    o.x = (uint32_t)f2bf(((float)q0.x - z) * sm * u0.x) |
          ((uint32_t)f2bf(((float)q0.y - z) * sm * u0.y) << 16);
    o.y = (uint32_t)f2bf(((float)q0.z - z) * sm * u0.z) |
          ((uint32_t)f2bf(((float)q0.w - z) * sm * u0.w) << 16);
    o.z = (uint32_t)f2bf(((float)q1.x - z) * sm * u1.x) |
          ((uint32_t)f2bf(((float)q1.y - z) * sm * u1.y) << 16);
    o.w = (uint32_t)f2bf(((float)q1.z - z) * sm * u1.z) |
          ((uint32_t)f2bf(((float)q1.w - z) * sm * u1.w) << 16);
    *((uint4*)(wb + (size_t)k * N_TOT + n0)) = o;
}

// ---- main GEMM: 256x256, ONE barrier per K-tile, compiler-scheduled waits ----
// 8 waves (2M x 4N), per-wave out 128x64, BK=64, double-buffered LDS.
// Per K-tile: __syncthreads() (vmcnt+lgkm drain is free: stages issued one
// full tile earlier) -> issue all 24 ds_read_b128 frags (A0,B0,A1,B1) ->
// issue all 8 global_load_lds stages for t+1 -> 4 MFMA quadrant clusters in
// fragment-arrival order, ks-outer. Compiler inserts minimal lgkmcnt(N)
// between reads and consuming MFMAs, so LDS service overlaps MFMA across the
// whole tile and waves desync freely between barriers.
// LDS XOR swizzle (proven R2): physical col = logical ^ ((row&7)*8 elems);
// linear gload_lds dest + inverse-swizzled global source + swizzled ds_read.
__global__ __launch_bounds__(512, 2) void gemm_kernel(const u16* __restrict__ Xb,
                                                      const u16* __restrict__ Wb,
                                                      const float* __restrict__ bias,
                                                      float* __restrict__ out) {
    __shared__ __align__(16) u16 lds[2 * SLOT_EL];   // 128 KiB

    // XCD-bijective swizzle: nwg = 512, divisible by 8
    const int bid = blockIdx.x;
    const int cpx = gridDim.x >> 3;
    const int swz = (bid & 7) * cpx + (bid >> 3);
    const int bm = swz >> 4;    // 32 M-tiles
    const int bn = swz & 15;    // 16 out-tiles

    const int tid  = threadIdx.x;
    const int w    = tid >> 6;
    const int lane = tid & 63;
    const int wm = w >> 2, wn = w & 3;

    // --- staging addressing: lane l, issue i covers LDS row (w*16 + i*8 + (l>>3)),
    // physical col (l&7)*16B; global col pre-swizzled: ((l&7)^(l>>3))*8 elems.
    const int scol = (((lane & 7) ^ (lane >> 3)) << 3);
    const u16* aS = Xb + (size_t)(bm * BM + w * 16 + (lane >> 3)) * N_TOT + scol;
    const u16* bS = Wb + (size_t)(bn * BN + w * 16 + (lane >> 3)) * N_TOT + scol;

    auto stage_tile = [&](int slot, int u) {
        u16* base = &lds[slot * SLOT_EL + w * 1024];
        #pragma unroll
        for (int h = 0; h < 2; ++h) {
            const u16* sa = aS + (size_t)(h * 128) * N_TOT + u * BK;
            const u16* sb = bS + (size_t)(h * 128) * N_TOT + u * BK;
            u16* da = base + h * HALF_EL;
            u16* db = base + B_OFF + h * HALF_EL;
            __builtin_amdgcn_global_load_lds(
                (const __attribute__((address_space(1))) uint32_t*)sa,
                (__attribute__((address_space(3))) uint32_t*)da, 16, 0, 0);
            __builtin_amdgcn_global_load_lds(
                (const __attribute__((address_space(1))) uint32_t*)(sa + (size_t)8 * N_TOT),
                (__attribute__((address_space(3))) uint32_t*)(da + 512), 16, 0, 0);
            __builtin_amdgcn_global_load_lds(
                (const __attribute__((address_space(1))) uint32_t*)sb,
                (__attribute__((address_space(3))) uint32_t*)db, 16, 0, 0);
            __builtin_amdgcn_global_load_lds(
                (const __attribute__((address_space(1))) uint32_t*)(sb + (size_t)8 * N_TOT),
                (__attribute__((address_space(3))) uint32_t*)(db + 512), 16, 0, 0);
        }
    };

    // --- fragment read addressing (u16 elements) ---
    const int cc0 = (((lane >> 4) << 3)) ^ ((lane & 7) << 3);
    const int rA  = ((wm << 4) + (lane & 15)) << 6;
    const int rB  = ((wn << 4) + (lane & 15)) << 6;

    f32x4 acc[2][2][4][2] = {};
    bf16x8 af[2][4][2];   // [mh][j][ks]
    bf16x8 bf[2][2][2];   // [nh][j2][ks]

    // prologue: stage tile 0 into slot 0
    stage_tile(0, 0);

    for (int t = 0; t < NT; ++t) {
        __syncthreads();   // drains vmcnt(0)+lgkmcnt(0); both free (1-tile gap)
        const int slot = (t & 1) * SLOT_EL;

        // issue all fragment reads, arrival order A0,B0 -> A1 -> B1
        #pragma unroll
        for (int j = 0; j < 4; ++j) {
            af[0][j][0] = *(const bf16x8*)&lds[slot + rA + j * 2048 + cc0];
            af[0][j][1] = *(const bf16x8*)&lds[slot + rA + j * 2048 + (cc0 ^ 32)];
        }
        #pragma unroll
        for (int j2 = 0; j2 < 2; ++j2) {
            bf[0][j2][0] = *(const bf16x8*)&lds[slot + B_OFF + rB + j2 * 4096 + cc0];
            bf[0][j2][1] = *(const bf16x8*)&lds[slot + B_OFF + rB + j2 * 4096 + (cc0 ^ 32)];
        }
        #pragma unroll
        for (int j = 0; j < 4; ++j) {
            af[1][j][0] = *(const bf16x8*)&lds[slot + HALF_EL + rA + j * 2048 + cc0];
            af[1][j][1] = *(const bf16x8*)&lds[slot + HALF_EL + rA + j * 2048 + (cc0 ^ 32)];
        }
        #pragma unroll
        for (int j2 = 0; j2 < 2; ++j2) {
            bf[1][j2][0] = *(const bf16x8*)&lds[slot + B_OFF + HALF_EL + rB + j2 * 4096 + cc0];
            bf[1][j2][1] = *(const bf16x8*)&lds[slot + B_OFF + HALF_EL + rB + j2 * 4096 + (cc0 ^ 32)];
        }

        // issue next tile's stages (deep pipeline: drained at next tile top)
        if (t < NT - 1) stage_tile((t + 1) & 1, t + 1);

        __builtin_amdgcn_s_setprio(1);
        // quadrant clusters in fragment-arrival order; ks-outer (independent
        // MFMAs back-to-back, dependent pair 8 instructions apart)
        #pragma unroll
        for (int ks = 0; ks < 2; ++ks)
            #pragma unroll
            for (int j = 0; j < 4; ++j)
                #pragma unroll
                for (int j2 = 0; j2 < 2; ++j2)
                    acc[0][0][j][j2] = __builtin_amdgcn_mfma_f32_16x16x32_bf16(
                        af[0][j][ks], bf[0][j2][ks], acc[0][0][j][j2], 0, 0, 0);
        #pragma unroll
        for (int ks = 0; ks < 2; ++ks)
            #pragma unroll
            for (int j = 0; j < 4; ++j)
                #pragma unroll
                for (int j2 = 0; j2 < 2; ++j2)
                    acc[1][0][j][j2] = __builtin_amdgcn_mfma_f32_16x16x32_bf16(
                        af[1][j][ks], bf[0][j2][ks], acc[1][0][j][j2], 0, 0, 0);
        #pragma unroll
        for (int ks = 0; ks < 2; ++ks)
            #pragma unroll
            for (int j = 0; j < 4; ++j)
                #pragma unroll
                for (int j2 = 0; j2 < 2; ++j2)
                    acc[0][1][j][j2] = __builtin_amdgcn_mfma_f32_16x16x32_bf16(
                        af[0][j][ks], bf[1][j2][ks], acc[0][1][j][j2], 0, 0, 0);
        #pragma unroll
        for (int ks = 0; ks < 2; ++ks)
            #pragma unroll
            for (int j = 0; j < 4; ++j)
                #pragma unroll
                for (int j2 = 0; j2 < 2; ++j2)
                    acc[1][1][j][j2] = __builtin_amdgcn_mfma_f32_16x16x32_bf16(
                        af[1][j][ks], bf[1][j2][ks], acc[1][1][j][j2], 0, 0, 0);
        __builtin_amdgcn_s_setprio(0);
    }

    // epilogue: C/D layout col = lane&15 (out-dim), row = (lane>>4)*4 + rr (M)
    #pragma unroll
    for (int mh_ = 0; mh_ < 2; ++mh_)
        #pragma unroll
        for (int j = 0; j < 4; ++j)
            #pragma unroll
            for (int rr = 0; rr < 4; ++rr) {
                const int row = bm * BM + mh_ * 128 + j * 32 + wm * 16 + ((lane >> 4) << 2) + rr;
                float* orow = out + (size_t)row * K_TOT;
                #pragma unroll
                for (int nh_ = 0; nh_ < 2; ++nh_)
                    #pragma unroll
                    for (int j2 = 0; j2 < 2; ++j2) {
                        const int col = bn * BN + nh_ * 128 + j2 * 64 + wn * 16 + (lane & 15);
                        orow[col] = acc[mh_][nh_][j][j2][rr] + bias[col];
                    }
            }
}

extern "C" void kernel_launch(void* const* d_in, const int* in_sizes, int n_in,
                              void* d_out, int out_size, void* d_ws, size_t ws_size,
                              hipStream_t stream) {
    const float* x      = (const float*)d_in[0];
    const float* scales = (const float*)d_in[1];
    const float* zeros  = (const float*)d_in[2];
    const float* mu1    = (const float*)d_in[3];
    const float* mu2    = (const float*)d_in[4];
    const float* bias   = (const float*)d_in[5];
    const int*   wq     = (const int*)d_in[6];
    float* out = (float*)d_out;

    u16* xb = (u16*)d_ws;                                 // 64 MiB
    u16* wb = (u16*)d_ws + (size_t)M_TOT * N_TOT;         // 32 MiB

    cvt_x_kernel<<<(M_TOT * N_TOT / 8) / 256, 256, 0, stream>>>(x, xb);
    deq_w_kernel<<<(K_TOT * N_TOT / 8) / 256, 256, 0, stream>>>(wq, scales, zeros, mu1, mu2, wb);
    gemm_kernel<<<(M_TOT / BM) * (K_TOT / BN), 512, 0, stream>>>(xb, wb, bias, out);
}